// Round 6
// baseline (361.907 us; speedup 1.0000x reference)
//
#include <hip/hip_runtime.h>

// Problem constants
#define B_  16
#define T_  12
#define N_  1000
#define F_  64
#define KC  3
#define O_  64
#define NP  1024            // padded N (both i and j dims)
#define KP  (KC * NP)       // 3072 combined contraction length per b
#define CC  (T_ * O_)       // 768 output columns per b
#define NKT 48              // KP / 64

typedef __bf16 bf16x8 __attribute__((ext_vector_type(8)));
typedef float  f32x4  __attribute__((ext_vector_type(4)));
typedef float  f32x16 __attribute__((ext_vector_type(16)));

__device__ __forceinline__ unsigned short f2bf(float f) {
  __bf16 h = (__bf16)f;                      // RNE convert
  return __builtin_bit_cast(unsigned short, h);
}

// ---------------------------------------------------------------------------
// Fragment-major layouts (MFMA 32x32x16 operand order, lane l holds
// [row=l&31][k=(l>>5)*8+e]):
//   AF[b][ibt(8)][wr(2)][mi(2)][kt(48)][ks(4)][lane(64)][e(8)]   (100.7 MB)
//   BF[b][cbt(6)][wc(2)][ci(2)][kt(48)][ks(4)][lane(64)][e(8)]   ( 75.5 MB)
// One (kt,ks) segment = 1 KB, contiguous per wave -> global_load_dwordx4
// streams with zero LDS and zero barriers in the GEMM K-loop.
// ---------------------------------------------------------------------------

// Prep (fused): blocks [0,4096) build AF from cheb*SAtt (transposed, 0-pad);
// blocks [4096,7168) build BF = x @ Theta per (b,t).
__global__ __launch_bounds__(256) void k_prep(
    const float* __restrict__ x, const float* __restrict__ SAtt,
    const float* __restrict__ cheb, const float* __restrict__ Theta,
    unsigned short* __restrict__ AF, unsigned short* __restrict__ BF) {
  __shared__ union {
    struct { unsigned short prod[KC][64][66]; } s1;                 // 25.9 KB
    struct {
      unsigned short thl[KC][64][72];   // Theta^T [k][o][f]
      unsigned short xl[64][72];        // x tile [j][f]
      unsigned short ot[64][72];        // out tile [o][j]
    } s2;                                                            // 45 KB
  } sm;
  const int tid = threadIdx.x;
  const int bid = blockIdx.x;
  const int l = tid & 63, ksw = tid >> 6;       // frag-write indices
  const int i32 = l & 31, lh = l >> 5;

  if (bid < 4096) {
    // ---- stage 1: A[b, i, K'=k*1024+j] = bf16(cheb[k,j,i]*SAtt[b,j,i]) ----
    const int ib64 = bid & 15, jb64 = (bid >> 4) & 15, b = bid >> 8;
    const int ib = ib64 * 64, jb = jb64 * 64;
    const int ibt = ib64 >> 1, wr = ib64 & 1;
    const int ii4 = (tid & 15) * 4, jr = tid >> 4;
#pragma unroll
    for (int p = 0; p < 4; ++p) {
      const int jj = p * 16 + jr;
      const int gj = jb + jj;
      const int gjc = gj < N_ ? gj : N_ - 1;
      const int gi = ib + ii4;                  // N_%4==0: f4 never straddles
      const bool iok = gi < N_;
      const bool ok = iok && (gj < N_);
      float4 s4 = make_float4(0.f, 0.f, 0.f, 0.f);
      if (iok) s4 = *(const float4*)&SAtt[((size_t)b * N_ + gjc) * N_ + gi];
#pragma unroll
      for (int k = 0; k < KC; ++k) {
        float4 c4 = make_float4(0.f, 0.f, 0.f, 0.f);
        if (iok) c4 = *(const float4*)&cheb[((size_t)k * N_ + gjc) * N_ + gi];
        ushort2 lo, hi;
        lo.x = ok ? f2bf(c4.x * s4.x) : (unsigned short)0;
        lo.y = ok ? f2bf(c4.y * s4.y) : (unsigned short)0;
        hi.x = ok ? f2bf(c4.z * s4.z) : (unsigned short)0;
        hi.y = ok ? f2bf(c4.w * s4.w) : (unsigned short)0;
        *(ushort2*)&sm.s1.prod[k][jj][ii4]     = lo;
        *(ushort2*)&sm.s1.prod[k][jj][ii4 + 2] = hi;
      }
    }
    __syncthreads();
    // frag-major write: thread (ksw,l) -> seg(ks=ksw), lane l; 1KB/wave
#pragma unroll
    for (int p = 0; p < 2; ++p) {               // p == mi (i32-half)
      const int iw = p * 32 + i32;
#pragma unroll
      for (int k = 0; k < KC; ++k) {
        const int kt = k * 16 + jb64;
        unsigned short v[8];
#pragma unroll
        for (int e = 0; e < 8; ++e)
          v[e] = sm.s1.prod[k][(ksw * 2 + lh) * 8 + e][iw];
        const size_t seg =
            ((((((size_t)b * 8 + ibt) * 2 + wr) * 2 + p) * NKT + kt) * 4 + ksw);
        *(uint4*)&AF[seg * 512 + l * 8] = *(uint4*)v;
      }
    }
  } else {
    // ---- stage 2: B[b, c=t*64+o, K'] = bf16(sum_f x[b,t,j,f]*Theta[k,f,o])
    const int b2 = bid - 4096;
    const int jb = (b2 & 15) * 64, bt = b2 >> 4;   // bt = b*T + t
    const int b = bt / T_, t = bt % T_;
    const int cbt = t >> 1, wcs = t & 1;
#pragma unroll
    for (int it = 0; it < 12; ++it) {
      const int e = (tid + it * 256) * 4;
      const int k = e >> 12, f = (e >> 6) & 63, o0 = e & 63;
      const float4 v = *(const float4*)&Theta[e];
      sm.s2.thl[k][o0 + 0][f] = f2bf(v.x);
      sm.s2.thl[k][o0 + 1][f] = f2bf(v.y);
      sm.s2.thl[k][o0 + 2][f] = f2bf(v.z);
      sm.s2.thl[k][o0 + 3][f] = f2bf(v.w);
    }
    const float* xrow = x + ((size_t)bt * N_ + jb) * F_;
#pragma unroll
    for (int p = 0; p < 4; ++p) {
      const int i4 = tid + p * 256;            // float4 index, 0..1023
      const int fl = i4 * 4, j = fl >> 6, f = fl & 63;
      float4 v;
      if (jb + j < N_) v = ((const float4*)xrow)[i4];
      else             v = make_float4(0.f, 0.f, 0.f, 0.f);
      ushort4 u;
      u.x = f2bf(v.x); u.y = f2bf(v.y); u.z = f2bf(v.z); u.w = f2bf(v.w);
      *(ushort4*)&sm.s2.xl[j][f] = u;
    }
    __syncthreads();

    const int w = tid >> 6, quad = l >> 4, lr = l & 15;
#pragma unroll
    for (int k = 0; k < KC; ++k) {
      f32x4 acc[4];
#pragma unroll
      for (int mi = 0; mi < 4; ++mi) acc[mi] = (f32x4){0.f, 0.f, 0.f, 0.f};
#pragma unroll
      for (int ks = 0; ks < 2; ++ks) {
        const int fo = ks * 32 + quad * 8;
        const bf16x8 bb = *(const bf16x8*)&sm.s2.xl[w * 16 + lr][fo];
#pragma unroll
        for (int mi = 0; mi < 4; ++mi) {
          const bf16x8 a = *(const bf16x8*)&sm.s2.thl[k][mi * 16 + lr][fo];
          acc[mi] =
              __builtin_amdgcn_mfma_f32_16x16x32_bf16(a, bb, acc[mi], 0, 0, 0);
        }
      }
      __syncthreads();                          // protect ot from prior readers
#pragma unroll
      for (int mi = 0; mi < 4; ++mi)
#pragma unroll
        for (int r = 0; r < 4; ++r)
          sm.s2.ot[mi * 16 + quad * 4 + r][w * 16 + lr] = f2bf(acc[mi][r]);
      __syncthreads();
      // frag-major write: per ci, thread (ksw,l) -> 1KB/wave segments
      const int kt = k * 16 + (jb >> 6);
#pragma unroll
      for (int ci = 0; ci < 2; ++ci) {
        const int o = ci * 32 + i32;
        unsigned short v[8];
#pragma unroll
        for (int e = 0; e < 8; ++e)
          v[e] = sm.s2.ot[o][ksw * 16 + lh * 8 + e];
        const size_t seg =
            ((((((size_t)b * 6 + cbt) * 2 + wcs) * 2 + ci) * NKT + kt) * 4 + ksw);
        *(uint4*)&BF[seg * 512 + l * 8] = *(uint4*)v;
      }
    }
  }
}

// ---------------------------------------------------------------------------
// Stage 3: per-b GEMM  C[i,c] = sum_{K'} A[i][K'] * B[c][K'] from frag-major
// AF/BF. 128x128 block tile, 4 waves x (64x64 as 2x2 of 32x32x16 MFMA).
// NO LDS, NO BARRIERS: each fragment is one contiguous 1KB global load;
// compiler interleaves loads and MFMAs with fine-grained vmcnt.
// 768 blocks = 3/CU, XCD-aware swizzle (2 b's per XCD).
// ---------------------------------------------------------------------------
__global__ __launch_bounds__(256, 3) void k_gemm(
    const unsigned short* __restrict__ AF, const unsigned short* __restrict__ BF,
    float* __restrict__ out) {
  const int tid = threadIdx.x;
  const int bid = blockIdx.x;
  const int xcd = bid & 7, s = bid >> 3;          // s = 0..95
  const int b = xcd * 2 + (s / 48);
  const int r48 = s % 48;
  const int ibt = r48 / 6, cbt = r48 % 6;

  const int w = tid >> 6, l = tid & 63;
  const int wr = w & 1, wc = w >> 1;
  const int l32 = l & 31, lh = l >> 5;

  // per-wave fragment stream bases (each (kt,ks) step advances 512 elems)
  const unsigned short* Aw[2];
  const unsigned short* Bw[2];
#pragma unroll
  for (int mi = 0; mi < 2; ++mi)
    Aw[mi] = AF +
        ((((size_t)b * 8 + ibt) * 2 + wr) * 2 + mi) * (NKT * 4 * 512) + l * 8;
#pragma unroll
  for (int ci = 0; ci < 2; ++ci)
    Bw[ci] = BF +
        ((((size_t)b * 6 + cbt) * 2 + wc) * 2 + ci) * (NKT * 4 * 512) + l * 8;

  f32x16 acc[2][2];
#pragma unroll
  for (int mi = 0; mi < 2; ++mi)
#pragma unroll
    for (int ci = 0; ci < 2; ++ci)
      acc[mi][ci] = (f32x16){0.f};

  for (int kt = 0; kt < NKT; ++kt) {
#pragma unroll
    for (int ks = 0; ks < 4; ++ks) {
      const size_t off = ((size_t)kt * 4 + ks) * 512;
      const bf16x8 a0 = *(const bf16x8*)(Aw[0] + off);
      const bf16x8 a1 = *(const bf16x8*)(Aw[1] + off);
      const bf16x8 b0 = *(const bf16x8*)(Bw[0] + off);
      const bf16x8 b1 = *(const bf16x8*)(Bw[1] + off);
      acc[0][0] = __builtin_amdgcn_mfma_f32_32x32x16_bf16(a0, b0, acc[0][0], 0, 0, 0);
      acc[0][1] = __builtin_amdgcn_mfma_f32_32x32x16_bf16(a0, b1, acc[0][1], 0, 0, 0);
      acc[1][0] = __builtin_amdgcn_mfma_f32_32x32x16_bf16(a1, b0, acc[1][0], 0, 0, 0);
      acc[1][1] = __builtin_amdgcn_mfma_f32_32x32x16_bf16(a1, b1, acc[1][1], 0, 0, 0);
    }
  }

  // epilogue: 32x32 C/D layout col=lane&31 (->c), row=(reg&3)+8*(reg>>2)+
  // 4*(lane>>5) (->i)  [m74/m101 verified]. ReLU fused.
  const int ib = ibt * 128, cb = cbt * 128;
#pragma unroll
  for (int mi = 0; mi < 2; ++mi) {
#pragma unroll
    for (int ci = 0; ci < 2; ++ci) {
      const int c = cb + wc * 64 + ci * 32 + l32;
      const int t = c >> 6, o = c & 63;      // 32-aligned segment: single t
      float* orow = out + ((size_t)(b * T_ + t) * N_) * O_ + o;
#pragma unroll
      for (int r = 0; r < 16; ++r) {
        const int i = ib + wr * 64 + mi * 32 + (r & 3) + 8 * (r >> 2) + 4 * lh;
        if (i < N_) {
          const float v = acc[mi][ci][r];
          orow[(size_t)i * O_] = v > 0.f ? v : 0.f;
        }
      }
    }
  }
}

// ---------------------------------------------------------------------------
extern "C" void kernel_launch(void* const* d_in, const int* in_sizes, int n_in,
                              void* d_out, int out_size, void* d_ws, size_t ws_size,
                              hipStream_t stream) {
  const float* x     = (const float*)d_in[0];
  const float* SAtt  = (const float*)d_in[1];
  const float* cheb  = (const float*)d_in[2];
  const float* Theta = (const float*)d_in[3];
  float* out = (float*)d_out;

  unsigned short* AF = (unsigned short*)d_ws;                 // 100.7 MB
  unsigned short* BF = AF + (size_t)B_ * NP * KC * NP;        //  75.5 MB

  k_prep<<<4096 + 3072, 256, 0, stream>>>(x, SAtt, cheb, Theta, AF, BF);
  k_gemm<<<768, 256, 0, stream>>>(AF, BF, out);
}